// Round 2
// baseline (800.431 us; speedup 1.0000x reference)
//
#include <hip/hip_runtime.h>
#include <stdint.h>

#define DIN   64
#define HDIM  64
#define EIN   16
#define EHID  128     // edge hidden width
#define HH    4096    // HDIM*HDIM
#define TC    8256    // BmatT rows: 8192 main + 64 bias
#define STEPS 3
#define NB    32      // nodes per fused block
#define TLCAP 512     // tile-list capacity (fallback walk if exceeded)

typedef short bf16x8 __attribute__((ext_vector_type(8)));
typedef float f32x4  __attribute__((ext_vector_type(4)));

__device__ __forceinline__ unsigned short f32_to_bf16(float f) {
    union { float f; uint32_t u; } v; v.f = f;
    uint32_t r = v.u + 0x7fffu + ((v.u >> 16) & 1u);   // RNE
    return (unsigned short)(r >> 16);
}

// ---- merged prologue: [0,nbN) node_mlp | [nbN,+nbE) edge_mlp(MFMA) | [+nbB) bmat | rest hist ----
__global__ void k_pro(const float* __restrict__ nf, const float* __restrict__ W0,
                      const float* __restrict__ b0, float* __restrict__ outb,
                      unsigned short* __restrict__ outbf,
                      const float* __restrict__ ef, const float* __restrict__ We1,
                      const float* __restrict__ be1, unsigned short* __restrict__ h,
                      const float* __restrict__ We2, const float* __restrict__ be2,
                      unsigned short* __restrict__ BmatT,
                      const int* __restrict__ src, const int* __restrict__ dst,
                      int* __restrict__ cntS, int* __restrict__ cntD,
                      int n_nodes, int n_edges, int nbN, int nbE, int nbB) {
    __shared__ float smem[DIN * HDIM];   // 16 KB (node path only)
    int b = blockIdx.x, tid = threadIdx.x;
    if (b < nbN) {
        // node MLP: out[n,o] = relu(n_feat[n,:]@W0[:,o]+b0[o]); 4 nodes/block
        for (int i = tid; i < DIN * HDIM; i += 256) smem[i] = W0[i];
        __syncthreads();
        int node = b * 4 + (tid >> 6);
        int o = tid & 63;
        if (node >= n_nodes) return;
        float xr = nf[node * DIN + o];
        float acc = b0[o];
#pragma unroll 8
        for (int i = 0; i < DIN; ++i)
            acc += __shfl(xr, i, 64) * smem[i * HDIM + o];
        float v = fmaxf(acc, 0.f);
        outb[node * HDIM + o] = v;
        outbf[node * HDIM + o] = f32_to_bf16(v);
    } else if (b < nbN + nbE) {
        // edge MLP via MFMA: 64 edges/block (16/wave), K=16 zero-padded to 32.
        // h stored with per-64-group col perm sigma (inverse baked into BmatT k-index).
        int wave = tid >> 6, lane = tid & 63;
        int r = lane & 15, q = lane >> 4;
        int e0 = (b - nbN) * 64 + wave * 16;
        if (e0 >= n_edges) return;           // wave-uniform
        bf16x8 afr = (bf16x8){};
        bf16x8 bfr[8];
#pragma unroll
        for (int nt = 0; nt < 8; ++nt) bfr[nt] = (bf16x8){};
        if (q < 2) {
            int ea = e0 + r; if (ea >= n_edges) ea = n_edges - 1;
            const float* xa = ef + (size_t)ea * EIN + q * 8;
#pragma unroll
            for (int j = 0; j < 8; ++j) afr[j] = (short)f32_to_bf16(xa[j]);
#pragma unroll
            for (int nt = 0; nt < 8; ++nt)
#pragma unroll
                for (int j = 0; j < 8; ++j)
                    bfr[nt][j] = (short)f32_to_bf16(We1[(q * 8 + j) * EHID + nt * 16 + r]);
        }
        f32x4 acc[8];
#pragma unroll
        for (int nt = 0; nt < 8; ++nt)
            acc[nt] = __builtin_amdgcn_mfma_f32_16x16x32_bf16(afr, bfr[nt], (f32x4){}, 0, 0, 0);
        float bias[8];
#pragma unroll
        for (int nt = 0; nt < 8; ++nt) bias[nt] = be1[nt * 16 + r];
#pragma unroll
        for (int rg = 0; rg < 4; ++rg) {
            int e = e0 + q * 4 + rg;         // C/D: col=lane&15, row=quad*4+reg
            if (e >= n_edges) continue;
            ushort4 pk0, pk1;
            pk0.x = f32_to_bf16(fmaxf(acc[0][rg] + bias[0], 0.f));
            pk0.y = f32_to_bf16(fmaxf(acc[1][rg] + bias[1], 0.f));
            pk0.z = f32_to_bf16(fmaxf(acc[2][rg] + bias[2], 0.f));
            pk0.w = f32_to_bf16(fmaxf(acc[3][rg] + bias[3], 0.f));
            pk1.x = f32_to_bf16(fmaxf(acc[4][rg] + bias[4], 0.f));
            pk1.y = f32_to_bf16(fmaxf(acc[5][rg] + bias[5], 0.f));
            pk1.z = f32_to_bf16(fmaxf(acc[6][rg] + bias[6], 0.f));
            pk1.w = f32_to_bf16(fmaxf(acc[7][rg] + bias[7], 0.f));
            *(ushort4*)(h + (size_t)e * EHID + 4 * r) = pk0;
            *(ushort4*)(h + (size_t)e * EHID + 64 + 4 * r) = pk1;
        }
    } else if (b < nbN + nbE + nbB) {
        // BmatT row m (< 8192): o = m>>7, nt = (m>>4)&7, r1 = m&15
        //   K = r1*8 + nt (h PHYSICAL column paired in phase-2)
        //   true channel k = sigma(K); column i = node-feature index.
        // Rows 8192..8255: bias, o = m-8192.
        int t = (b - nbN - nbE) * 256 + tid;
        if (t >= TC * 64) return;
        int m = t >> 6, i = t & 63;
        float v;
        if (m < 8192) {
            int o  = m >> 7;
            int K  = ((m & 15) << 3) | ((m >> 4) & 7);
            int k  = (K & 64) + ((K & 3) << 4) + ((K >> 2) & 15);
            v = We2[k * HH + i * 64 + o];
        } else {
            v = be2[i * 64 + (m - 8192)];
        }
        BmatT[m * 64 + i] = f32_to_bf16(v);
    } else {
        // histogram src and dst
        int e = (b - nbN - nbE - nbB) * 256 + tid;
        if (e >= n_edges) return;
        atomicAdd(&cntS[src[e]], 1);
        atomicAdd(&cntD[dst[e]], 1);
    }
}

// Fused T+msg, v2: block = 32 src nodes, 8 o-chunks of 8 cols.
//   phase1: T[32n][128K][8o] chunk -> LDS (B held in 128 VGPRs, prefetched
//           during previous phase2 so loads fly under compute)
//   phase2: msg[:, oc*8..+8) for this block's edges; 3-stage gather pipeline
//           (permS 2 tiles ahead, h-frags 1 tile ahead) from a per-block tile list.
// Chunk order rotated by blockIdx to stagger L2 banks. LDS slot XOR-swizzle as before.
__global__ __launch_bounds__(256, 2)
void k_fused(const unsigned short* __restrict__ outbf,
             const unsigned short* __restrict__ BmatT,
             const unsigned short* __restrict__ h,
             const int* __restrict__ offS, const int* __restrict__ permS,
             float* __restrict__ msg, int n_nodes) {
    __shared__ short Tlds[NB * 1024];   // 64 KB: per node 8 o x 16 slots x 16B
    __shared__ float Tb[NB * 64];       // 8 KB bias (all 64 cols)
    __shared__ int   tl[TLCAP];         // 2 KB tile list: (ni<<20)|j0
    __shared__ int   ends_s[NB];
    __shared__ int   s_tcnt;

    int tid = threadIdx.x;
    int wave = tid >> 6, lane = tid & 63;
    int r = lane & 15, q = lane >> 4;
    int n0 = blockIdx.x * NB;
    int bid = blockIdx.x;
    int nlim = n_nodes - n0; if (nlim > NB) nlim = NB;

    if (tid == 0) s_tcnt = 0;
    __syncthreads();
    if (tid < nlim) {
        int beg = offS[n0 + tid], end = offS[n0 + tid + 1];
        ends_s[tid] = end;
        int c = (end - beg + 15) >> 4;
        if (c > 0) {
            int pos = atomicAdd(&s_tcnt, c);
            if (pos + c <= TLCAP)
                for (int k2 = 0; k2 < c; ++k2)
                    tl[pos + k2] = (tid << 20) | (beg + k2 * 16);
        }
    }

    // A fragments for 2 M-tiles (32 nodes), persist across chunks
    bf16x8 afrA[2], afrB[2];
#pragma unroll
    for (int mt = 0; mt < 2; ++mt) {
        int na = n0 + mt * 16 + r; if (na >= n_nodes) na = n_nodes - 1;
        afrA[mt] = *(const bf16x8*)(outbf + (size_t)na * 64 + q * 8);
        afrB[mt] = *(const bf16x8*)(outbf + (size_t)na * 64 + 32 + q * 8);
    }

    // chunk-0 B prefetch into registers (32 x 16B in flight per wave)
    bf16x8 bv0[16], bv1[16];
    {
        int ocp = bid & 7;
#pragma unroll
        for (int o = 0; o < 2; ++o)
#pragma unroll
            for (int nt = 0; nt < 8; ++nt) {
                int row = (ocp * 8 + wave * 2 + o) * 128 + nt * 16 + r;
                bv0[o * 8 + nt] = *(const bf16x8*)(BmatT + (size_t)row * 64 + q * 8);
                bv1[o * 8 + nt] = *(const bf16x8*)(BmatT + (size_t)row * 64 + 32 + q * 8);
            }
    }

    // bias tile: wave covers cols wave*16 + r, both M-tiles
    {
        size_t cofs = (size_t)(8192 + wave * 16 + r) * 64;
        bf16x8 bb0 = *(const bf16x8*)(BmatT + cofs + q * 8);
        bf16x8 bb1 = *(const bf16x8*)(BmatT + cofs + 32 + q * 8);
#pragma unroll
        for (int mt = 0; mt < 2; ++mt) {
            f32x4 aB = __builtin_amdgcn_mfma_f32_16x16x32_bf16(afrA[mt], bb0, (f32x4){}, 0, 0, 0);
            aB = __builtin_amdgcn_mfma_f32_16x16x32_bf16(afrB[mt], bb1, aB, 0, 0, 0);
#pragma unroll
            for (int rg = 0; rg < 4; ++rg)
                Tb[(mt * 16 + q * 4 + rg) * 64 + wave * 16 + r] = aB[rg];
        }
    }

    for (int oc = 0; oc < 8; ++oc) {
        int ocp = (oc + bid) & 7;
        __syncthreads();   // prev phase2 done reading Tlds; B regs drained (vmcnt)
        // ---- phase 1: MFMA prefetched B -> pack -> LDS ----
#pragma unroll
        for (int o = 0; o < 2; ++o) {
            int o_in = wave * 2 + o;
#pragma unroll
            for (int mt = 0; mt < 2; ++mt) {
                f32x4 acc[8];
#pragma unroll
                for (int nt = 0; nt < 8; ++nt) {
                    acc[nt] = __builtin_amdgcn_mfma_f32_16x16x32_bf16(afrA[mt], bv0[o * 8 + nt], (f32x4){}, 0, 0, 0);
                    acc[nt] = __builtin_amdgcn_mfma_f32_16x16x32_bf16(afrB[mt], bv1[o * 8 + nt], acc[nt], 0, 0, 0);
                }
#pragma unroll
                for (int rg = 0; rg < 4; ++rg) {
                    bf16x8 pk;
#pragma unroll
                    for (int nt = 0; nt < 8; ++nt) pk[nt] = (short)f32_to_bf16(acc[nt][rg]);
                    *(bf16x8*)((char*)Tlds + (mt * 16 + q * 4 + rg) * 2048 + o_in * 256
                               + ((r ^ (o_in & 7)) & 15) * 16) = pk;
                }
            }
        }
        __syncthreads();
        // issue next chunk's B loads now: they fly under phase 2, drain at next barrier
        if (oc < 7) {
            int ocn = (oc + 1 + bid) & 7;
#pragma unroll
            for (int o = 0; o < 2; ++o)
#pragma unroll
                for (int nt = 0; nt < 8; ++nt) {
                    int row = (ocn * 8 + wave * 2 + o) * 128 + nt * 16 + r;
                    bv0[o * 8 + nt] = *(const bf16x8*)(BmatT + (size_t)row * 64 + q * 8);
                    bv1[o * 8 + nt] = *(const bf16x8*)(BmatT + (size_t)row * 64 + 32 + q * 8);
                }
        }
        // ---- phase 2: msg cols [ocp*8, +8) ----
        int cnt = s_tcnt;
        int colr = r & 7;
        if (cnt <= TLCAP) {
            // 3-stage pipeline: N(permS) -> B(h loads) -> C(compute)
            int tC = wave;
            int niC = 0, j0C = 0, endC = 0, eB = 0, niB = 0, j0B = 0, endB = 0;
            bf16x8 hC0{}, hC1{}, hC2{}, hC3{};
            if (tC < cnt) {
                int pk2 = tl[tC]; niC = pk2 >> 20; j0C = pk2 & 0xFFFFF; endC = ends_s[niC];
                int jc = j0C + r; if (jc >= endC) jc = endC - 1;
                int e = permS[jc];
                const unsigned short* he = h + (size_t)e * EHID;
                hC0 = *(const bf16x8*)(he + q * 8);
                hC1 = *(const bf16x8*)(he + 32 + q * 8);
                hC2 = *(const bf16x8*)(he + 64 + q * 8);
                hC3 = *(const bf16x8*)(he + 96 + q * 8);
            }
            int tB = tC + 4;
            if (tB < cnt) {
                int pk2 = tl[tB]; niB = pk2 >> 20; j0B = pk2 & 0xFFFFF; endB = ends_s[niB];
                int jc = j0B + r; if (jc >= endB) jc = endB - 1;
                eB = permS[jc];
            }
            while (tC < cnt) {
                int tN = tC + 8;
                int niN = 0, j0N = 0, endN = 0, eN = 0;
                if (tN < cnt) {
                    int pk2 = tl[tN]; niN = pk2 >> 20; j0N = pk2 & 0xFFFFF; endN = ends_s[niN];
                    int jc = j0N + r; if (jc >= endN) jc = endN - 1;
                    eN = permS[jc];
                }
                bf16x8 hB0{}, hB1{}, hB2{}, hB3{};
                if (tB < cnt) {
                    const unsigned short* he = h + (size_t)eB * EHID;
                    hB0 = *(const bf16x8*)(he + q * 8);
                    hB1 = *(const bf16x8*)(he + 32 + q * 8);
                    hB2 = *(const bf16x8*)(he + 64 + q * 8);
                    hB3 = *(const bf16x8*)(he + 96 + q * 8);
                }
                // compute tile C
                f32x4 acc = {};
                {
                    const char* base = (const char*)Tlds + niC * 2048 + colr * 256;
                    bf16x8 b0 = *(const bf16x8*)(base + (((0 * 4 + q) ^ colr) & 15) * 16);
                    acc = __builtin_amdgcn_mfma_f32_16x16x32_bf16(hC0, b0, acc, 0, 0, 0);
                    bf16x8 b1 = *(const bf16x8*)(base + (((1 * 4 + q) ^ colr) & 15) * 16);
                    acc = __builtin_amdgcn_mfma_f32_16x16x32_bf16(hC1, b1, acc, 0, 0, 0);
                    bf16x8 b2 = *(const bf16x8*)(base + (((2 * 4 + q) ^ colr) & 15) * 16);
                    acc = __builtin_amdgcn_mfma_f32_16x16x32_bf16(hC2, b2, acc, 0, 0, 0);
                    bf16x8 b3 = *(const bf16x8*)(base + (((3 * 4 + q) ^ colr) & 15) * 16);
                    acc = __builtin_amdgcn_mfma_f32_16x16x32_bf16(hC3, b3, acc, 0, 0, 0);
                }
                float bias = Tb[niC * 64 + ocp * 8 + colr];
                if (r < 8) {
#pragma unroll
                    for (int rg = 0; rg < 4; ++rg) {
                        int jr = j0C + q * 4 + rg;
                        if (jr < endC) {
                            int er = permS[jr];
                            msg[(size_t)er * 64 + ocp * 8 + r] = acc[rg] + bias;
                        }
                    }
                }
                tC = tB; niC = niB; j0C = j0B; endC = endB;
                hC0 = hB0; hC1 = hB1; hC2 = hB2; hC3 = hB3;
                tB = tN; niB = niN; j0B = j0N; endB = endN; eB = eN;
            }
        } else {
            // fallback walk (guaranteed-correct path, list overflow)
            int tt = 0;
            for (int ni = 0; ni < nlim; ++ni) {
                int beg = offS[n0 + ni], end = offS[n0 + ni + 1];
                for (int j0 = beg; j0 < end; j0 += 16, ++tt) {
                    if ((tt & 3) != wave) continue;
                    int jc = j0 + r; if (jc >= end) jc = end - 1;
                    int e = permS[jc];
                    const unsigned short* he = h + (size_t)e * EHID;
                    f32x4 acc = {};
#pragma unroll
                    for (int ks = 0; ks < 4; ++ks) {
                        bf16x8 afr = *(const bf16x8*)(he + ks * 32 + q * 8);
                        bf16x8 bfr = *(const bf16x8*)((char*)Tlds + ni * 2048 + colr * 256
                                       + (((ks * 4 + q) ^ colr) & 15) * 16);
                        acc = __builtin_amdgcn_mfma_f32_16x16x32_bf16(afr, bfr, acc, 0, 0, 0);
                    }
                    float bias = Tb[ni * 64 + ocp * 8 + colr];
                    if (r < 8) {
#pragma unroll
                        for (int rg = 0; rg < 4; ++rg) {
                            int jr = j0 + q * 4 + rg;
                            if (jr < end) {
                                int er = permS[jr];
                                msg[(size_t)er * 64 + ocp * 8 + r] = acc[rg] + bias;
                            }
                        }
                    }
                }
            }
        }
    }
}

// exclusive prefix sum (one block per array; blockIdx.x: 0=S, 1=D)
__global__ void k_scan(const int* __restrict__ cntS, const int* __restrict__ cntD,
                       int* __restrict__ offS, int* __restrict__ offD,
                       int* __restrict__ curS, int* __restrict__ curD, int n, int total) {
    const int* cnt = blockIdx.x ? cntD : cntS;
    int* off = blockIdx.x ? offD : offS;
    int* cur = blockIdx.x ? curD : curS;
    __shared__ int part[256];
    int tid = threadIdx.x;
    int chunk = (n + 255) / 256;
    int c0 = tid * chunk, c1 = c0 + chunk; if (c1 > n) c1 = n; if (c0 > n) c0 = n;
    int s = 0;
    for (int i = c0; i < c1; ++i) s += cnt[i];
    part[tid] = s;
    __syncthreads();
    for (int st = 1; st < 256; st <<= 1) {
        int v = (tid >= st) ? part[tid - st] : 0;
        __syncthreads();
        part[tid] += v;
        __syncthreads();
    }
    int run = tid ? part[tid - 1] : 0;
    for (int i = c0; i < c1; ++i) { off[i] = run; cur[i] = run; run += cnt[i]; }
    if (tid == 0) off[n] = total;
}

__global__ void k_perm(const int* __restrict__ src, const int* __restrict__ dst,
                       int* __restrict__ curS, int* __restrict__ curD,
                       int* __restrict__ permS, int* __restrict__ permD, int n_edges) {
    int e = blockIdx.x * 256 + threadIdx.x;
    if (e >= n_edges) return;
    permS[atomicAdd(&curS[src[e]], 1)] = e;
    permD[atomicAdd(&curD[dst[e]], 1)] = e;
}

// per dst-node wave: out[d] = relu(sum msg + cbias); atomic-free. msg is PLAIN.
__global__ void k_agg(const float* __restrict__ msg, const int* __restrict__ offD,
                      const int* __restrict__ permD, const float* __restrict__ cbias,
                      float* __restrict__ outb, unsigned short* __restrict__ outbf, int n_nodes) {
    int wave = threadIdx.x >> 6, lane = threadIdx.x & 63;
    int d = blockIdx.x * 4 + wave;
    if (d >= n_nodes) return;
    float acc = 0.f;
    int end = offD[d + 1];
    for (int j = offD[d]; j < end; ++j)
        acc += msg[(size_t)permD[j] * 64 + lane];
    float v = fmaxf(acc + cbias[lane], 0.f);
    outb[(size_t)d * 64 + lane] = v;
    outbf[(size_t)d * 64 + lane] = f32_to_bf16(v);
}

// grid MUST be 64 blocks (row stride 256 hardcoded)
__global__ void k_bn_stats(const float* __restrict__ out, float* __restrict__ stat, int n_nodes) {
    __shared__ float s1[256], s2[256];
    int tid = threadIdx.x;
    int f = tid & 63, g = tid >> 6;
    float sum = 0.f, ss = 0.f;
    for (int r = blockIdx.x * 4 + g; r < n_nodes; r += 256) {
        float v = out[r * HDIM + f];
        sum += v; ss += v * v;
    }
    s1[tid] = sum; s2[tid] = ss;
    __syncthreads();
    if (tid < 64) {
        float A = s1[tid] + s1[64 + tid] + s1[128 + tid] + s1[192 + tid];
        float B = s2[tid] + s2[64 + tid] + s2[128 + tid] + s2[192 + tid];
        atomicAdd(&stat[tid], A);
        atomicAdd(&stat[64 + tid], B);
    }
}

// bn_final fused in: every thread derives scale/shift from stat (identical arith)
__global__ void k_bn_apply(const float* __restrict__ out, const float* __restrict__ stat,
                           const float* __restrict__ gamma, const float* __restrict__ beta,
                           float* __restrict__ y, int n, int n_nodes) {
    int t = blockIdx.x * 256 + threadIdx.x;
    if (t >= n) return;
    int f = t & 63;
    float mean = stat[f] / n_nodes;
    float var  = stat[64 + f] / n_nodes - mean * mean;   // population var
    float inv  = rsqrtf(var + 1e-5f);
    float scale = gamma[f] * inv;
    float shift = beta[f] - mean * scale;
    y[t] = out[t] * scale + shift;
}

extern "C" void kernel_launch(void* const* d_in, const int* in_sizes, int n_in,
                              void* d_out, int out_size, void* d_ws, size_t ws_size,
                              hipStream_t stream) {
    const float* nf    = (const float*)d_in[0];
    const float* ef    = (const float*)d_in[1];
    const int*   src   = (const int*)d_in[2];
    const int*   dst   = (const int*)d_in[3];
    const float* W0    = (const float*)d_in[4];
    const float* b0    = (const float*)d_in[5];
    const float* We1   = (const float*)d_in[6];
    const float* be1   = (const float*)d_in[7];
    const float* We2   = (const float*)d_in[8];
    const float* be2   = (const float*)d_in[9];
    const float* cbias = (const float*)d_in[10];
    const float* gamma = (const float*)d_in[11];
    const float* beta  = (const float*)d_in[12];
    (void)n_in; (void)out_size; (void)ws_size;

    int n_nodes = in_sizes[0] / DIN;   // 10000
    int n_edges = in_sizes[2];         // 100000

    char* ws = (char*)d_ws;
    size_t off = 0;
    auto carve = [&](size_t bytes) -> void* {
        void* p = ws + off;
        off = (off + bytes + 255) & ~(size_t)255;
        return p;
    };
    unsigned short* h     = (unsigned short*)carve((size_t)n_edges * EHID * 2);  // 25.6 MB
    float*          msg   = (float*)carve((size_t)n_edges * 64 * 4);             // 25.6 MB
    float*          outb  = (float*)carve((size_t)n_nodes * HDIM * 4);
    unsigned short* outbf = (unsigned short*)carve((size_t)n_nodes * HDIM * 2);
    unsigned short* BmatT = (unsigned short*)carve((size_t)TC * 64 * 2);
    int*            offS  = (int*)carve((size_t)(n_nodes + 1) * 4);
    int*            offD  = (int*)carve((size_t)(n_nodes + 1) * 4);
    int*            curS  = (int*)carve((size_t)n_nodes * 4);
    int*            curD  = (int*)carve((size_t)n_nodes * 4);
    int*            permS = (int*)carve((size_t)n_edges * 4);
    int*            permD = (int*)carve((size_t)n_edges * 4);
    float*          stat  = (float*)carve(128 * 4 + (size_t)2 * n_nodes * 4); // stat + cntS + cntD
    int*            cntS  = (int*)(stat + 128);
    int*            cntD  = cntS + n_nodes;

    hipMemsetAsync(stat, 0, 128 * 4 + (size_t)2 * n_nodes * 4, stream);

    int nbN = (n_nodes + 3) / 4;            // 2500
    int nbE = (n_edges + 63) / 64;          // 1563 (MFMA edge path: 64 edges/block)
    int nbB = (TC * 64 + 255) / 256;        // 2064
    int nbH = (n_edges + 255) / 256;        // 391
    k_pro<<<dim3(nbN + nbE + nbB + nbH), 256, 0, stream>>>(
        nf, W0, b0, outb, outbf, ef, We1, be1, h, We2, be2, BmatT,
        src, dst, cntS, cntD, n_nodes, n_edges, nbN, nbE, nbB);
    k_scan<<<dim3(2), 256, 0, stream>>>(cntS, cntD, offS, offD, curS, curD, n_nodes, n_edges);
    k_perm<<<dim3((n_edges + 255) / 256), 256, 0, stream>>>(src, dst, curS, curD, permS, permD, n_edges);

    int nbF = (n_nodes + NB - 1) / NB;      // 313 fused blocks
    for (int step = 0; step < STEPS; ++step) {
        k_fused<<<dim3(nbF), 256, 0, stream>>>(outbf, BmatT, h, offS, permS, msg, n_nodes);
        k_agg<<<dim3((n_nodes + 3) / 4), 256, 0, stream>>>(msg, offD, permD, cbias, outb, outbf, n_nodes);
    }

    k_bn_stats<<<dim3(64), 256, 0, stream>>>(outb, stat, n_nodes);
    k_bn_apply<<<dim3((n_nodes * HDIM + 255) / 256), 256, 0, stream>>>(
        outb, stat, gamma, beta, (float*)d_out, n_nodes * HDIM, n_nodes);
}

// Round 3
// 502.549 us; speedup vs baseline: 1.5927x; 1.5927x over previous
//
#include <hip/hip_runtime.h>
#include <stdint.h>

#define DIN   64
#define HDIM  64
#define EIN   16
#define EHID  128     // edge hidden width
#define HH    4096    // HDIM*HDIM
#define TC    8256    // T cols: 8192 main + 64 bias
#define STEPS 3

typedef short bf16x8 __attribute__((ext_vector_type(8)));
typedef float f32x4  __attribute__((ext_vector_type(4)));

__device__ __forceinline__ unsigned short f32_to_bf16(float f) {
    union { float f; uint32_t u; } v; v.f = f;
    uint32_t r = v.u + 0x7fffu + ((v.u >> 16) & 1u);   // RNE
    return (unsigned short)(r >> 16);
}
__device__ __forceinline__ float bfu_to_f(unsigned short u) {
    union { uint32_t u; float f; } v; v.u = (uint32_t)u << 16; return v.f;
}

// ---- merged prologue: [0,nbN) node_mlp | [nbN,+nbE) edge_mlp(MFMA) | [+nbB) bmat | rest hist ----
__global__ void k_pro(const float* __restrict__ nf, const float* __restrict__ W0,
                      const float* __restrict__ b0, float* __restrict__ outb,
                      unsigned short* __restrict__ outbf,
                      const float* __restrict__ ef, const float* __restrict__ We1,
                      const float* __restrict__ be1, unsigned short* __restrict__ h,
                      const float* __restrict__ We2, const float* __restrict__ be2,
                      unsigned short* __restrict__ BmatT,
                      const int* __restrict__ src, const int* __restrict__ dst,
                      int* __restrict__ cntS, int* __restrict__ cntD,
                      int n_nodes, int n_edges, int nbN, int nbE, int nbB) {
    __shared__ float smem[DIN * HDIM];   // 16 KB (node path only)
    int b = blockIdx.x, tid = threadIdx.x;
    if (b < nbN) {
        // node MLP: out[n,o] = relu(n_feat[n,:]@W0[:,o]+b0[o]); 4 nodes/block
        for (int i = tid; i < DIN * HDIM; i += 256) smem[i] = W0[i];
        __syncthreads();
        int node = b * 4 + (tid >> 6);
        int o = tid & 63;
        if (node >= n_nodes) return;
        float xr = nf[node * DIN + o];
        float acc = b0[o];
#pragma unroll 8
        for (int i = 0; i < DIN; ++i)
            acc += __shfl(xr, i, 64) * smem[i * HDIM + o];
        float v = fmaxf(acc, 0.f);
        outb[node * HDIM + o] = v;
        outbf[node * HDIM + o] = f32_to_bf16(v);
    } else if (b < nbN + nbE) {
        // edge MLP via MFMA: 64 edges/block (16/wave), K=16 zero-padded to 32.
        // h stored with per-64-group col perm sigma (inverse baked into BmatT k-index).
        int wave = tid >> 6, lane = tid & 63;
        int r = lane & 15, q = lane >> 4;
        int e0 = (b - nbN) * 64 + wave * 16;
        if (e0 >= n_edges) return;           // wave-uniform
        bf16x8 afr = (bf16x8){};
        bf16x8 bfr[8];
#pragma unroll
        for (int nt = 0; nt < 8; ++nt) bfr[nt] = (bf16x8){};
        if (q < 2) {
            int ea = e0 + r; if (ea >= n_edges) ea = n_edges - 1;
            const float* xa = ef + (size_t)ea * EIN + q * 8;
#pragma unroll
            for (int j = 0; j < 8; ++j) afr[j] = (short)f32_to_bf16(xa[j]);
#pragma unroll
            for (int nt = 0; nt < 8; ++nt)
#pragma unroll
                for (int j = 0; j < 8; ++j)
                    bfr[nt][j] = (short)f32_to_bf16(We1[(q * 8 + j) * EHID + nt * 16 + r]);
        }
        f32x4 acc[8];
#pragma unroll
        for (int nt = 0; nt < 8; ++nt)
            acc[nt] = __builtin_amdgcn_mfma_f32_16x16x32_bf16(afr, bfr[nt], (f32x4){}, 0, 0, 0);
        float bias[8];
#pragma unroll
        for (int nt = 0; nt < 8; ++nt) bias[nt] = be1[nt * 16 + r];
#pragma unroll
        for (int rg = 0; rg < 4; ++rg) {
            int e = e0 + q * 4 + rg;         // C/D: col=lane&15, row=quad*4+reg
            if (e >= n_edges) continue;
            ushort4 pk0, pk1;
            pk0.x = f32_to_bf16(fmaxf(acc[0][rg] + bias[0], 0.f));
            pk0.y = f32_to_bf16(fmaxf(acc[1][rg] + bias[1], 0.f));
            pk0.z = f32_to_bf16(fmaxf(acc[2][rg] + bias[2], 0.f));
            pk0.w = f32_to_bf16(fmaxf(acc[3][rg] + bias[3], 0.f));
            pk1.x = f32_to_bf16(fmaxf(acc[4][rg] + bias[4], 0.f));
            pk1.y = f32_to_bf16(fmaxf(acc[5][rg] + bias[5], 0.f));
            pk1.z = f32_to_bf16(fmaxf(acc[6][rg] + bias[6], 0.f));
            pk1.w = f32_to_bf16(fmaxf(acc[7][rg] + bias[7], 0.f));
            *(ushort4*)(h + (size_t)e * EHID + 4 * r) = pk0;
            *(ushort4*)(h + (size_t)e * EHID + 64 + 4 * r) = pk1;
        }
    } else if (b < nbN + nbE + nbB) {
        // BmatT: epilogue-pack perm (128-group main / 64-group bias) + T'' layout + h-perm sigma
        int t = (b - nbN - nbE) * 256 + tid;
        if (t >= TC * 64) return;
        int c = t >> 6, i = t & 63;
        int m;
        if (c < 8192) {
            int g = c & 127;                       // mfma col nt*16+r -> mem col 8r+nt
            m = (c & ~127) + 8 * (g & 15) + (g >> 4);
        } else {
            int g = c & 63;                        // bias block keeps 4r+nt
            m = (c & ~63) + 4 * (g & 15) + (g >> 4);
        }
        float v;
        if (m < 8192) {
            int p = ((m >> 11) << 5) | (m & 31);                     // stored h position
            int k = (p & 64) + ((p & 3) << 4) + ((p >> 2) & 15);     // true h channel
            int o = (m >> 5) & 63;
            v = We2[k * HH + i * 64 + o];
        } else {
            v = be2[i * 64 + (m - 8192)];
        }
        BmatT[t] = f32_to_bf16(v);
    } else {
        // histogram src and dst
        int e = (b - nbN - nbE - nbB) * 256 + tid;
        if (e >= n_edges) return;
        atomicAdd(&cntS[src[e]], 1);
        atomicAdd(&cntD[dst[e]], 1);
    }
}

// T[n, m] = sum_i x[n,i]*B[i,m], bf16 out in T'' layout.
// Main path (blockIdx.x<16): wave = 128-col group, 8 B-tiles in regs.
// NEW: MFMA epilogue goes via a double-buffered 16KB LDS tile so each global
// store instruction is ONE contiguous 1KB row burst (was 4x 256B scattered rows).
// Tail block 16: 64 bias cols, old 4r+nt packing (unchanged).
__global__ void k_T(const unsigned short* __restrict__ outbf, const unsigned short* __restrict__ BmatT,
                    unsigned short* __restrict__ T, int n0, int n1) {
    __shared__ uint4 stile[2][16 * 64];   // 2 x 16 rows x 64 16B-slots = 32 KB
    int wave = threadIdx.x >> 6, lane = threadIdx.x & 63;
    int r = lane & 15, q = lane >> 4;
    int eb = n0 + blockIdx.y * 128;
    if (blockIdx.x < 16) {
        int cb = blockIdx.x * 512 + wave * 128;
        bf16x8 bfr[8][2];
#pragma unroll
        for (int nt = 0; nt < 8; ++nt) {
            size_t cofs = (size_t)(cb + nt * 16 + r) * 64;
            bfr[nt][0] = *(const bf16x8*)(BmatT + cofs + q * 8);
            bfr[nt][1] = *(const bf16x8*)(BmatT + cofs + 32 + q * 8);
        }
        for (int mt = 0; mt < 8; ++mt) {
            int e = eb + mt * 16 + r;
            if (e >= n1) e = n1 - 1;
            bf16x8 afr0 = *(const bf16x8*)(outbf + (size_t)e * 64 + q * 8);
            bf16x8 afr1 = *(const bf16x8*)(outbf + (size_t)e * 64 + 32 + q * 8);
            f32x4 acc[8];
#pragma unroll
            for (int nt = 0; nt < 8; ++nt) {
                acc[nt] = __builtin_amdgcn_mfma_f32_16x16x32_bf16(afr0, bfr[nt][0], (f32x4){}, 0, 0, 0);
                acc[nt] = __builtin_amdgcn_mfma_f32_16x16x32_bf16(afr1, bfr[nt][1], acc[nt], 0, 0, 0);
            }
            uint4* buf = stile[mt & 1];
#pragma unroll
            for (int rg = 0; rg < 4; ++rg) {
                int row = q * 4 + rg;            // C/D: col=lane&15, row=quad*4+reg
                ushort4 pa, pb;
                pa.x = f32_to_bf16(acc[0][rg]); pa.y = f32_to_bf16(acc[1][rg]);
                pa.z = f32_to_bf16(acc[2][rg]); pa.w = f32_to_bf16(acc[3][rg]);
                pb.x = f32_to_bf16(acc[4][rg]); pb.y = f32_to_bf16(acc[5][rg]);
                pb.z = f32_to_bf16(acc[6][rg]); pb.w = f32_to_bf16(acc[7][rg]);
                uint4 pk = { ((uint32_t)pa.y << 16) | pa.x, ((uint32_t)pa.w << 16) | pa.z,
                             ((uint32_t)pb.y << 16) | pb.x, ((uint32_t)pb.w << 16) | pb.z };
                // slot = wave*16 + r covers cols cb+8r..+8 ; XOR row-swizzle kills bank aliasing
                buf[row * 64 + ((wave * 16 + r) ^ (row & 7))] = pk;
            }
            __syncthreads();
            // cooperative writes: wave w drains rows w*4..w*4+3, 1KB contiguous each
#pragma unroll
            for (int rr = 0; rr < 4; ++rr) {
                int row = wave * 4 + rr;
                int n = eb + mt * 16 + row;
                if (n < n1) {
                    uint4 v = buf[row * 64 + (lane ^ (row & 7))];
                    *(uint4*)(T + (size_t)(n - n0) * TC + blockIdx.x * 512 + lane * 8) = v;
                }
            }
        }
    } else {
        if (wave != 0) return;               // bias tail: 64 cols only
        int cb = 8192;
        bf16x8 bfr[4][2];
#pragma unroll
        for (int nt = 0; nt < 4; ++nt) {
            size_t cofs = (size_t)(cb + nt * 16 + r) * 64;
            bfr[nt][0] = *(const bf16x8*)(BmatT + cofs + q * 8);
            bfr[nt][1] = *(const bf16x8*)(BmatT + cofs + 32 + q * 8);
        }
#pragma unroll
        for (int mt = 0; mt < 8; ++mt) {
            int e = eb + mt * 16 + r;
            if (e >= n1) e = n1 - 1;
            bf16x8 afr0 = *(const bf16x8*)(outbf + (size_t)e * 64 + q * 8);
            bf16x8 afr1 = *(const bf16x8*)(outbf + (size_t)e * 64 + 32 + q * 8);
            f32x4 acc[4];
#pragma unroll
            for (int nt = 0; nt < 4; ++nt) {
                acc[nt] = __builtin_amdgcn_mfma_f32_16x16x32_bf16(afr0, bfr[nt][0], (f32x4){}, 0, 0, 0);
                acc[nt] = __builtin_amdgcn_mfma_f32_16x16x32_bf16(afr1, bfr[nt][1], acc[nt], 0, 0, 0);
            }
#pragma unroll
            for (int rg = 0; rg < 4; ++rg) {
                int n = eb + mt * 16 + q * 4 + rg;
                if (n >= n1) continue;
                ushort4 pk;
                pk.x = f32_to_bf16(acc[0][rg]);
                pk.y = f32_to_bf16(acc[1][rg]);
                pk.z = f32_to_bf16(acc[2][rg]);
                pk.w = f32_to_bf16(acc[3][rg]);
                *(ushort4*)(T + (size_t)(n - n0) * TC + cb + 4 * r) = pk;
            }
        }
    }
}

// per src-node wave, MFMA: msg[tile of 16 edges][64 o] = h[edges, 0:128] @ T''[n]
// msg stored col-permuted IN BF16: mem col 4r+nt holds mfma col nt*16+r;
// k_agg applies the inverse perm.
__global__ void k_msg(const unsigned short* __restrict__ h, const unsigned short* __restrict__ T,
                      const int* __restrict__ offS, const int* __restrict__ permS,
                      unsigned short* __restrict__ msg, int n0, int n1) {
    int wave = threadIdx.x >> 6, lane = threadIdx.x & 63;
    int n = n0 + blockIdx.x * 4 + wave;
    if (n >= n1) return;
    int beg = offS[n], end = offS[n + 1];
    if (beg == end) return;
    int r = lane & 15, q = lane >> 4;
    const unsigned short* Tb = T + (size_t)(n - n0) * TC;
    float bias[4];
#pragma unroll
    for (int nt = 0; nt < 4; ++nt)
        bias[nt] = bfu_to_f(Tb[8192 + nt * 16 + r]);
    for (int j0 = beg; j0 < end; j0 += 16) {
        int jc = j0 + r; if (jc >= end) jc = end - 1;
        int e = permS[jc];
        const unsigned short* he = h + (size_t)e * EHID;
        f32x4 acc[4] = {};
#pragma unroll
        for (int s = 0; s < 4; ++s) {        // K = 128 = 4*32
            bf16x8 afr = *(const bf16x8*)(he + s * 32 + q * 8);
#pragma unroll
            for (int nt = 0; nt < 4; ++nt) {
                bf16x8 bfr = *(const bf16x8*)(Tb + s * 2048 + (nt * 16 + r) * 32 + q * 8);
                acc[nt] = __builtin_amdgcn_mfma_f32_16x16x32_bf16(afr, bfr, acc[nt], 0, 0, 0);
            }
        }
#pragma unroll
        for (int rg = 0; rg < 4; ++rg) {
            int jr = j0 + q * 4 + rg;
            if (jr >= end) continue;
            int er = permS[jr];
            ushort4 pk;
            pk.x = f32_to_bf16(acc[0][rg] + bias[0]);
            pk.y = f32_to_bf16(acc[1][rg] + bias[1]);
            pk.z = f32_to_bf16(acc[2][rg] + bias[2]);
            pk.w = f32_to_bf16(acc[3][rg] + bias[3]);
            *(ushort4*)(msg + (size_t)er * 64 + 4 * r) = pk;
        }
    }
}

// exclusive prefix sum (one block per array; blockIdx.x: 0=S, 1=D)
__global__ void k_scan(const int* __restrict__ cntS, const int* __restrict__ cntD,
                       int* __restrict__ offS, int* __restrict__ offD,
                       int* __restrict__ curS, int* __restrict__ curD, int n, int total) {
    const int* cnt = blockIdx.x ? cntD : cntS;
    int* off = blockIdx.x ? offD : offS;
    int* cur = blockIdx.x ? curD : curS;
    __shared__ int part[256];
    int tid = threadIdx.x;
    int chunk = (n + 255) / 256;
    int c0 = tid * chunk, c1 = c0 + chunk; if (c1 > n) c1 = n; if (c0 > n) c0 = n;
    int s = 0;
    for (int i = c0; i < c1; ++i) s += cnt[i];
    part[tid] = s;
    __syncthreads();
    for (int st = 1; st < 256; st <<= 1) {
        int v = (tid >= st) ? part[tid - st] : 0;
        __syncthreads();
        part[tid] += v;
        __syncthreads();
    }
    int run = tid ? part[tid - 1] : 0;
    for (int i = c0; i < c1; ++i) { off[i] = run; cur[i] = run; run += cnt[i]; }
    if (tid == 0) off[n] = total;
}

__global__ void k_perm(const int* __restrict__ src, const int* __restrict__ dst,
                       int* __restrict__ curS, int* __restrict__ curD,
                       int* __restrict__ permS, int* __restrict__ permD, int n_edges) {
    int e = blockIdx.x * 256 + threadIdx.x;
    if (e >= n_edges) return;
    permS[atomicAdd(&curS[src[e]], 1)] = e;
    permD[atomicAdd(&curD[dst[e]], 1)] = e;
}

// per dst-node wave: out[d] = relu(sum msg + cbias); atomic-free.
// msg cols are stored permuted bf16: lane's stored col l is semantic o=(l&3)*16+(l>>2).
__global__ void k_agg(const unsigned short* __restrict__ msg, const int* __restrict__ offD,
                      const int* __restrict__ permD, const float* __restrict__ cbias,
                      float* __restrict__ outb, unsigned short* __restrict__ outbf, int n_nodes) {
    int wave = threadIdx.x >> 6, lane = threadIdx.x & 63;
    int d = blockIdx.x * 4 + wave;
    if (d >= n_nodes) return;
    int o = (lane & 3) * 16 + (lane >> 2);
    float acc = 0.f;
    int end = offD[d + 1];
    for (int j = offD[d]; j < end; ++j)
        acc += bfu_to_f(msg[(size_t)permD[j] * 64 + lane]);
    float v = fmaxf(acc + cbias[o], 0.f);
    outb[(size_t)d * 64 + o] = v;
    outbf[(size_t)d * 64 + o] = f32_to_bf16(v);
}

// grid MUST be 64 blocks (row stride 256 hardcoded)
__global__ void k_bn_stats(const float* __restrict__ out, float* __restrict__ stat, int n_nodes) {
    __shared__ float s1[256], s2[256];
    int tid = threadIdx.x;
    int f = tid & 63, g = tid >> 6;
    float sum = 0.f, ss = 0.f;
    for (int r = blockIdx.x * 4 + g; r < n_nodes; r += 256) {
        float v = out[r * HDIM + f];
        sum += v; ss += v * v;
    }
    s1[tid] = sum; s2[tid] = ss;
    __syncthreads();
    if (tid < 64) {
        float A = s1[tid] + s1[64 + tid] + s1[128 + tid] + s1[192 + tid];
        float B = s2[tid] + s2[64 + tid] + s2[128 + tid] + s2[192 + tid];
        atomicAdd(&stat[tid], A);
        atomicAdd(&stat[64 + tid], B);
    }
}

// bn_final fused in: every thread derives scale/shift from stat (identical arith)
__global__ void k_bn_apply(const float* __restrict__ out, const float* __restrict__ stat,
                           const float* __restrict__ gamma, const float* __restrict__ beta,
                           float* __restrict__ y, int n, int n_nodes) {
    int t = blockIdx.x * 256 + threadIdx.x;
    if (t >= n) return;
    int f = t & 63;
    float mean = stat[f] / n_nodes;
    float var  = stat[64 + f] / n_nodes - mean * mean;   // population var
    float inv  = rsqrtf(var + 1e-5f);
    float scale = gamma[f] * inv;
    float shift = beta[f] - mean * scale;
    y[t] = out[t] * scale + shift;
}

extern "C" void kernel_launch(void* const* d_in, const int* in_sizes, int n_in,
                              void* d_out, int out_size, void* d_ws, size_t ws_size,
                              hipStream_t stream) {
    const float* nf    = (const float*)d_in[0];
    const float* ef    = (const float*)d_in[1];
    const int*   src   = (const int*)d_in[2];
    const int*   dst   = (const int*)d_in[3];
    const float* W0    = (const float*)d_in[4];
    const float* b0    = (const float*)d_in[5];
    const float* We1   = (const float*)d_in[6];
    const float* be1   = (const float*)d_in[7];
    const float* We2   = (const float*)d_in[8];
    const float* be2   = (const float*)d_in[9];
    const float* cbias = (const float*)d_in[10];
    const float* gamma = (const float*)d_in[11];
    const float* beta  = (const float*)d_in[12];
    (void)n_in; (void)out_size;

    int n_nodes = in_sizes[0] / DIN;   // 10000
    int n_edges = in_sizes[2];         // 100000

    char* ws = (char*)d_ws;
    size_t off = 0;
    auto carve = [&](size_t bytes) -> void* {
        void* p = ws + off;
        off = (off + bytes + 255) & ~(size_t)255;
        return p;
    };
    unsigned short* h     = (unsigned short*)carve((size_t)n_edges * EHID * 2);  // 25.6 MB
    unsigned short* msg   = (unsigned short*)carve((size_t)n_edges * 64 * 2);    // 12.8 MB (bf16)
    float*          outb  = (float*)carve((size_t)n_nodes * HDIM * 4);
    unsigned short* outbf = (unsigned short*)carve((size_t)n_nodes * HDIM * 2);
    unsigned short* BmatT = (unsigned short*)carve((size_t)TC * 64 * 2);
    int*            offS  = (int*)carve((size_t)(n_nodes + 1) * 4);
    int*            offD  = (int*)carve((size_t)(n_nodes + 1) * 4);
    int*            curS  = (int*)carve((size_t)n_nodes * 4);
    int*            curD  = (int*)carve((size_t)n_nodes * 4);
    int*            permS = (int*)carve((size_t)n_edges * 4);
    int*            permD = (int*)carve((size_t)n_edges * 4);
    float*          stat  = (float*)carve(128 * 4 + (size_t)2 * n_nodes * 4); // stat + cntS + cntD
    int*            cntS  = (int*)(stat + 128);
    int*            cntD  = cntS + n_nodes;
    unsigned short* T     = (unsigned short*)(ws + off);
    size_t avail = ws_size > off ? ws_size - off : 0;
    long tcap = (long)(avail / ((size_t)TC * 2));   // ws-capacity bound (node rows)
    if (tcap > n_nodes) tcap = n_nodes;
    if (tcap < 64) tcap = 64;
    long tchunk = tcap;   // R7: chunking measured neutral -> single chunk, fewer launches

    hipMemsetAsync(stat, 0, 128 * 4 + (size_t)2 * n_nodes * 4, stream);

    int nbN = (n_nodes + 3) / 4;            // 2500
    int nbE = (n_edges + 63) / 64;          // 1563 (MFMA edge path: 64 edges/block)
    int nbB = (TC * 64 + 255) / 256;        // 2064
    int nbH = (n_edges + 255) / 256;        // 391
    k_pro<<<dim3(nbN + nbE + nbB + nbH), 256, 0, stream>>>(
        nf, W0, b0, outb, outbf, ef, We1, be1, h, We2, be2, BmatT,
        src, dst, cntS, cntD, n_nodes, n_edges, nbN, nbE, nbB);
    k_scan<<<dim3(2), 256, 0, stream>>>(cntS, cntD, offS, offD, curS, curD, n_nodes, n_edges);
    k_perm<<<dim3((n_edges + 255) / 256), 256, 0, stream>>>(src, dst, curS, curD, permS, permD, n_edges);

    for (int step = 0; step < STEPS; ++step) {
        for (long n0 = 0; n0 < n_nodes; n0 += tchunk) {
            long n1 = n0 + tchunk; if (n1 > n_nodes) n1 = n_nodes;
            long cnt = n1 - n0;
            k_T<<<dim3(17, (cnt + 127) / 128), 256, 0, stream>>>(
                outbf, BmatT, T, (int)n0, (int)n1);
            k_msg<<<dim3((cnt + 3) / 4), 256, 0, stream>>>(
                h, T, offS, permS, msg, (int)n0, (int)n1);
        }
        k_agg<<<dim3((n_nodes + 3) / 4), 256, 0, stream>>>(msg, offD, permD, cbias, outb, outbf, n_nodes);
    }

    k_bn_stats<<<dim3(64), 256, 0, stream>>>(outb, stat, n_nodes);
    k_bn_apply<<<dim3((n_nodes * HDIM + 255) / 256), 256, 0, stream>>>(
        outb, stat, gamma, beta, (float*)d_out, n_nodes * HDIM, n_nodes);
}

// Round 4
// 422.703 us; speedup vs baseline: 1.8936x; 1.1889x over previous
//
#include <hip/hip_runtime.h>
#include <stdint.h>

#define DIN   64
#define HDIM  64
#define EIN   16
#define EHID  128     // edge hidden width
#define HH    4096    // HDIM*HDIM
#define TC    8256    // T cols: 8192 main + 64 bias
#define STEPS 3

typedef short bf16x8 __attribute__((ext_vector_type(8)));
typedef float f32x4  __attribute__((ext_vector_type(4)));

__device__ __forceinline__ unsigned short f32_to_bf16(float f) {
    union { float f; uint32_t u; } v; v.f = f;
    uint32_t r = v.u + 0x7fffu + ((v.u >> 16) & 1u);   // RNE
    return (unsigned short)(r >> 16);
}
__device__ __forceinline__ float bfu_to_f(unsigned short u) {
    union { uint32_t u; float f; } v; v.u = (uint32_t)u << 16; return v.f;
}

// ---- merged prologue: [0,nbN) node_mlp | [nbN,+nbE) edge_mlp(MFMA) | [+nbB) bmat | rest hist ----
__global__ void k_pro(const float* __restrict__ nf, const float* __restrict__ W0,
                      const float* __restrict__ b0, float* __restrict__ outb,
                      unsigned short* __restrict__ outbf,
                      const float* __restrict__ ef, const float* __restrict__ We1,
                      const float* __restrict__ be1, unsigned short* __restrict__ h,
                      const float* __restrict__ We2, const float* __restrict__ be2,
                      unsigned short* __restrict__ BmatT,
                      const int* __restrict__ src, const int* __restrict__ dst,
                      int* __restrict__ cntS, int* __restrict__ cntD,
                      int n_nodes, int n_edges, int nbN, int nbE, int nbB) {
    __shared__ float smem[DIN * HDIM];   // 16 KB (node path only)
    int b = blockIdx.x, tid = threadIdx.x;
    if (b < nbN) {
        // node MLP: out[n,o] = relu(n_feat[n,:]@W0[:,o]+b0[o]); 4 nodes/block
        for (int i = tid; i < DIN * HDIM; i += 256) smem[i] = W0[i];
        __syncthreads();
        int node = b * 4 + (tid >> 6);
        int o = tid & 63;
        if (node >= n_nodes) return;
        float xr = nf[node * DIN + o];
        float acc = b0[o];
#pragma unroll 8
        for (int i = 0; i < DIN; ++i)
            acc += __shfl(xr, i, 64) * smem[i * HDIM + o];
        float v = fmaxf(acc, 0.f);
        outb[node * HDIM + o] = v;
        outbf[node * HDIM + o] = f32_to_bf16(v);
    } else if (b < nbN + nbE) {
        // edge MLP via MFMA: 64 edges/block (16/wave), K=16 zero-padded to 32.
        // h stored with per-64-group col perm sigma (inverse baked into BmatT k-index).
        int wave = tid >> 6, lane = tid & 63;
        int r = lane & 15, q = lane >> 4;
        int e0 = (b - nbN) * 64 + wave * 16;
        if (e0 >= n_edges) return;           // wave-uniform
        bf16x8 afr = (bf16x8){};
        bf16x8 bfr[8];
#pragma unroll
        for (int nt = 0; nt < 8; ++nt) bfr[nt] = (bf16x8){};
        if (q < 2) {
            int ea = e0 + r; if (ea >= n_edges) ea = n_edges - 1;
            const float* xa = ef + (size_t)ea * EIN + q * 8;
#pragma unroll
            for (int j = 0; j < 8; ++j) afr[j] = (short)f32_to_bf16(xa[j]);
#pragma unroll
            for (int nt = 0; nt < 8; ++nt)
#pragma unroll
                for (int j = 0; j < 8; ++j)
                    bfr[nt][j] = (short)f32_to_bf16(We1[(q * 8 + j) * EHID + nt * 16 + r]);
        }
        f32x4 acc[8];
#pragma unroll
        for (int nt = 0; nt < 8; ++nt)
            acc[nt] = __builtin_amdgcn_mfma_f32_16x16x32_bf16(afr, bfr[nt], (f32x4){}, 0, 0, 0);
        float bias[8];
#pragma unroll
        for (int nt = 0; nt < 8; ++nt) bias[nt] = be1[nt * 16 + r];
#pragma unroll
        for (int rg = 0; rg < 4; ++rg) {
            int e = e0 + q * 4 + rg;         // C/D: col=lane&15, row=quad*4+reg
            if (e >= n_edges) continue;
            ushort4 pk0, pk1;
            pk0.x = f32_to_bf16(fmaxf(acc[0][rg] + bias[0], 0.f));
            pk0.y = f32_to_bf16(fmaxf(acc[1][rg] + bias[1], 0.f));
            pk0.z = f32_to_bf16(fmaxf(acc[2][rg] + bias[2], 0.f));
            pk0.w = f32_to_bf16(fmaxf(acc[3][rg] + bias[3], 0.f));
            pk1.x = f32_to_bf16(fmaxf(acc[4][rg] + bias[4], 0.f));
            pk1.y = f32_to_bf16(fmaxf(acc[5][rg] + bias[5], 0.f));
            pk1.z = f32_to_bf16(fmaxf(acc[6][rg] + bias[6], 0.f));
            pk1.w = f32_to_bf16(fmaxf(acc[7][rg] + bias[7], 0.f));
            *(ushort4*)(h + (size_t)e * EHID + 4 * r) = pk0;
            *(ushort4*)(h + (size_t)e * EHID + 64 + 4 * r) = pk1;
        }
    } else if (b < nbN + nbE + nbB) {
        // BmatT: epilogue-pack perm (128-group main / 64-group bias) + T'' layout + h-perm sigma
        int t = (b - nbN - nbE) * 256 + tid;
        if (t >= TC * 64) return;
        int c = t >> 6, i = t & 63;
        int m;
        if (c < 8192) {
            int g = c & 127;                       // mfma col nt*16+r -> mem col 8r+nt
            m = (c & ~127) + 8 * (g & 15) + (g >> 4);
        } else {
            int g = c & 63;                        // bias block keeps 4r+nt
            m = (c & ~63) + 4 * (g & 15) + (g >> 4);
        }
        float v;
        if (m < 8192) {
            int p = ((m >> 11) << 5) | (m & 31);                     // stored h position
            int k = (p & 64) + ((p & 3) << 4) + ((p >> 2) & 15);     // true h channel
            int o = (m >> 5) & 63;
            v = We2[k * HH + i * 64 + o];
        } else {
            v = be2[i * 64 + (m - 8192)];
        }
        BmatT[t] = f32_to_bf16(v);
    } else {
        // histogram src and dst
        int e = (b - nbN - nbE - nbB) * 256 + tid;
        if (e >= n_edges) return;
        atomicAdd(&cntS[src[e]], 1);
        atomicAdd(&cntD[dst[e]], 1);
    }
}

// T[n, m] = sum_i x[n,i]*B[i,m], bf16 out in T'' layout.
// Main path (blockIdx.x<16): wave = 128-col group, 8 B-tiles pinned in regs.
// __launch_bounds__(256,4) raises the VGPR cap to ~128 so bfr[8][2] (64 VGPR)
// + acc[8] (32 VGPR) stay RESIDENT across the 8 mt iterations (at the default
// budget the compiler allocated 64 VGPR and re-loaded B every iteration —
// that was the measured 45µs/3.6TB/s wall). Direct exact-payload stores.
// Tail block 16: 64 bias cols, 4r+nt packing.
__global__ __launch_bounds__(256, 4)
void k_T(const unsigned short* __restrict__ outbf, const unsigned short* __restrict__ BmatT,
         unsigned short* __restrict__ T, int n0, int n1) {
    int wave = threadIdx.x >> 6, lane = threadIdx.x & 63;
    int r = lane & 15, q = lane >> 4;
    int eb = n0 + blockIdx.y * 128;
    if (blockIdx.x < 16) {
        int cb = blockIdx.x * 512 + wave * 128;
        bf16x8 bfr[8][2];
#pragma unroll
        for (int nt = 0; nt < 8; ++nt) {
            size_t cofs = (size_t)(cb + nt * 16 + r) * 64;
            bfr[nt][0] = *(const bf16x8*)(BmatT + cofs + q * 8);
            bfr[nt][1] = *(const bf16x8*)(BmatT + cofs + 32 + q * 8);
        }
#pragma unroll
        for (int mt = 0; mt < 8; ++mt) {
            int e = eb + mt * 16 + r;
            if (e >= n1) e = n1 - 1;
            bf16x8 afr0 = *(const bf16x8*)(outbf + (size_t)e * 64 + q * 8);
            bf16x8 afr1 = *(const bf16x8*)(outbf + (size_t)e * 64 + 32 + q * 8);
            f32x4 acc[8];
#pragma unroll
            for (int nt = 0; nt < 8; ++nt) {
                acc[nt] = __builtin_amdgcn_mfma_f32_16x16x32_bf16(afr0, bfr[nt][0], (f32x4){}, 0, 0, 0);
                acc[nt] = __builtin_amdgcn_mfma_f32_16x16x32_bf16(afr1, bfr[nt][1], acc[nt], 0, 0, 0);
            }
#pragma unroll
            for (int rg = 0; rg < 4; ++rg) {
                int n = eb + mt * 16 + q * 4 + rg;   // C/D: col=lane&15, row=quad*4+reg
                if (n >= n1) continue;
                ushort4 pa, pb;
                pa.x = f32_to_bf16(acc[0][rg]); pa.y = f32_to_bf16(acc[1][rg]);
                pa.z = f32_to_bf16(acc[2][rg]); pa.w = f32_to_bf16(acc[3][rg]);
                pb.x = f32_to_bf16(acc[4][rg]); pb.y = f32_to_bf16(acc[5][rg]);
                pb.z = f32_to_bf16(acc[6][rg]); pb.w = f32_to_bf16(acc[7][rg]);
                uint4 pk = { ((uint32_t)pa.y << 16) | pa.x, ((uint32_t)pa.w << 16) | pa.z,
                             ((uint32_t)pb.y << 16) | pb.x, ((uint32_t)pb.w << 16) | pb.z };
                *(uint4*)(T + (size_t)(n - n0) * TC + cb + 8 * r) = pk;
            }
        }
    } else {
        if (wave != 0) return;               // bias tail: 64 cols only
        int cb = 8192;
        bf16x8 bfr[4][2];
#pragma unroll
        for (int nt = 0; nt < 4; ++nt) {
            size_t cofs = (size_t)(cb + nt * 16 + r) * 64;
            bfr[nt][0] = *(const bf16x8*)(BmatT + cofs + q * 8);
            bfr[nt][1] = *(const bf16x8*)(BmatT + cofs + 32 + q * 8);
        }
#pragma unroll
        for (int mt = 0; mt < 8; ++mt) {
            int e = eb + mt * 16 + r;
            if (e >= n1) e = n1 - 1;
            bf16x8 afr0 = *(const bf16x8*)(outbf + (size_t)e * 64 + q * 8);
            bf16x8 afr1 = *(const bf16x8*)(outbf + (size_t)e * 64 + 32 + q * 8);
            f32x4 acc[4];
#pragma unroll
            for (int nt = 0; nt < 4; ++nt) {
                acc[nt] = __builtin_amdgcn_mfma_f32_16x16x32_bf16(afr0, bfr[nt][0], (f32x4){}, 0, 0, 0);
                acc[nt] = __builtin_amdgcn_mfma_f32_16x16x32_bf16(afr1, bfr[nt][1], acc[nt], 0, 0, 0);
            }
#pragma unroll
            for (int rg = 0; rg < 4; ++rg) {
                int n = eb + mt * 16 + q * 4 + rg;
                if (n >= n1) continue;
                ushort4 pk;
                pk.x = f32_to_bf16(acc[0][rg]);
                pk.y = f32_to_bf16(acc[1][rg]);
                pk.z = f32_to_bf16(acc[2][rg]);
                pk.w = f32_to_bf16(acc[3][rg]);
                *(ushort4*)(T + (size_t)(n - n0) * TC + cb + 4 * r) = pk;
            }
        }
    }
}

// per src-node wave, MFMA: msg[tile of 16 edges][64 o] = h[edges, 0:128] @ T''[n]
// msg stored col-permuted IN BF16: mem col 4r+nt holds mfma col nt*16+r;
// k_agg applies the inverse perm.
__global__ void k_msg(const unsigned short* __restrict__ h, const unsigned short* __restrict__ T,
                      const int* __restrict__ offS, const int* __restrict__ permS,
                      unsigned short* __restrict__ msg, int n0, int n1) {
    int wave = threadIdx.x >> 6, lane = threadIdx.x & 63;
    int n = n0 + blockIdx.x * 4 + wave;
    if (n >= n1) return;
    int beg = offS[n], end = offS[n + 1];
    if (beg == end) return;
    int r = lane & 15, q = lane >> 4;
    const unsigned short* Tb = T + (size_t)(n - n0) * TC;
    float bias[4];
#pragma unroll
    for (int nt = 0; nt < 4; ++nt)
        bias[nt] = bfu_to_f(Tb[8192 + nt * 16 + r]);
    for (int j0 = beg; j0 < end; j0 += 16) {
        int jc = j0 + r; if (jc >= end) jc = end - 1;
        int e = permS[jc];
        const unsigned short* he = h + (size_t)e * EHID;
        f32x4 acc[4] = {};
#pragma unroll
        for (int s = 0; s < 4; ++s) {        // K = 128 = 4*32
            bf16x8 afr = *(const bf16x8*)(he + s * 32 + q * 8);
#pragma unroll
            for (int nt = 0; nt < 4; ++nt) {
                bf16x8 bfr = *(const bf16x8*)(Tb + s * 2048 + (nt * 16 + r) * 32 + q * 8);
                acc[nt] = __builtin_amdgcn_mfma_f32_16x16x32_bf16(afr, bfr, acc[nt], 0, 0, 0);
            }
        }
#pragma unroll
        for (int rg = 0; rg < 4; ++rg) {
            int jr = j0 + q * 4 + rg;
            if (jr >= end) continue;
            int er = permS[jr];
            ushort4 pk;
            pk.x = f32_to_bf16(acc[0][rg] + bias[0]);
            pk.y = f32_to_bf16(acc[1][rg] + bias[1]);
            pk.z = f32_to_bf16(acc[2][rg] + bias[2]);
            pk.w = f32_to_bf16(acc[3][rg] + bias[3]);
            *(ushort4*)(msg + (size_t)er * 64 + 4 * r) = pk;
        }
    }
}

// exclusive prefix sum (one block per array; blockIdx.x: 0=S, 1=D)
__global__ void k_scan(const int* __restrict__ cntS, const int* __restrict__ cntD,
                       int* __restrict__ offS, int* __restrict__ offD,
                       int* __restrict__ curS, int* __restrict__ curD, int n, int total) {
    const int* cnt = blockIdx.x ? cntD : cntS;
    int* off = blockIdx.x ? offD : offS;
    int* cur = blockIdx.x ? curD : curS;
    __shared__ int part[256];
    int tid = threadIdx.x;
    int chunk = (n + 255) / 256;
    int c0 = tid * chunk, c1 = c0 + chunk; if (c1 > n) c1 = n; if (c0 > n) c0 = n;
    int s = 0;
    for (int i = c0; i < c1; ++i) s += cnt[i];
    part[tid] = s;
    __syncthreads();
    for (int st = 1; st < 256; st <<= 1) {
        int v = (tid >= st) ? part[tid - st] : 0;
        __syncthreads();
        part[tid] += v;
        __syncthreads();
    }
    int run = tid ? part[tid - 1] : 0;
    for (int i = c0; i < c1; ++i) { off[i] = run; cur[i] = run; run += cnt[i]; }
    if (tid == 0) off[n] = total;
}

__global__ void k_perm(const int* __restrict__ src, const int* __restrict__ dst,
                       int* __restrict__ curS, int* __restrict__ curD,
                       int* __restrict__ permS, int* __restrict__ permD, int n_edges) {
    int e = blockIdx.x * 256 + threadIdx.x;
    if (e >= n_edges) return;
    permS[atomicAdd(&curS[src[e]], 1)] = e;
    permD[atomicAdd(&curD[dst[e]], 1)] = e;
}

// per dst-node wave: out[d] = relu(sum msg + cbias); atomic-free.
// msg cols are stored permuted bf16: lane's stored col l is semantic o=(l&3)*16+(l>>2).
__global__ void k_agg(const unsigned short* __restrict__ msg, const int* __restrict__ offD,
                      const int* __restrict__ permD, const float* __restrict__ cbias,
                      float* __restrict__ outb, unsigned short* __restrict__ outbf, int n_nodes) {
    int wave = threadIdx.x >> 6, lane = threadIdx.x & 63;
    int d = blockIdx.x * 4 + wave;
    if (d >= n_nodes) return;
    int o = (lane & 3) * 16 + (lane >> 2);
    float acc = 0.f;
    int end = offD[d + 1];
    for (int j = offD[d]; j < end; ++j)
        acc += bfu_to_f(msg[(size_t)permD[j] * 64 + lane]);
    float v = fmaxf(acc + cbias[o], 0.f);
    outb[(size_t)d * 64 + o] = v;
    outbf[(size_t)d * 64 + o] = f32_to_bf16(v);
}

// grid MUST be 64 blocks (row stride 256 hardcoded)
__global__ void k_bn_stats(const float* __restrict__ out, float* __restrict__ stat, int n_nodes) {
    __shared__ float s1[256], s2[256];
    int tid = threadIdx.x;
    int f = tid & 63, g = tid >> 6;
    float sum = 0.f, ss = 0.f;
    for (int r = blockIdx.x * 4 + g; r < n_nodes; r += 256) {
        float v = out[r * HDIM + f];
        sum += v; ss += v * v;
    }
    s1[tid] = sum; s2[tid] = ss;
    __syncthreads();
    if (tid < 64) {
        float A = s1[tid] + s1[64 + tid] + s1[128 + tid] + s1[192 + tid];
        float B = s2[tid] + s2[64 + tid] + s2[128 + tid] + s2[192 + tid];
        atomicAdd(&stat[tid], A);
        atomicAdd(&stat[64 + tid], B);
    }
}

// bn_final fused in: every thread derives scale/shift from stat (identical arith)
__global__ void k_bn_apply(const float* __restrict__ out, const float* __restrict__ stat,
                           const float* __restrict__ gamma, const float* __restrict__ beta,
                           float* __restrict__ y, int n, int n_nodes) {
    int t = blockIdx.x * 256 + threadIdx.x;
    if (t >= n) return;
    int f = t & 63;
    float mean = stat[f] / n_nodes;
    float var  = stat[64 + f] / n_nodes - mean * mean;   // population var
    float inv  = rsqrtf(var + 1e-5f);
    float scale = gamma[f] * inv;
    float shift = beta[f] - mean * scale;
    y[t] = out[t] * scale + shift;
}

extern "C" void kernel_launch(void* const* d_in, const int* in_sizes, int n_in,
                              void* d_out, int out_size, void* d_ws, size_t ws_size,
                              hipStream_t stream) {
    const float* nf    = (const float*)d_in[0];
    const float* ef    = (const float*)d_in[1];
    const int*   src   = (const int*)d_in[2];
    const int*   dst   = (const int*)d_in[3];
    const float* W0    = (const float*)d_in[4];
    const float* b0    = (const float*)d_in[5];
    const float* We1   = (const float*)d_in[6];
    const float* be1   = (const float*)d_in[7];
    const float* We2   = (const float*)d_in[8];
    const float* be2   = (const float*)d_in[9];
    const float* cbias = (const float*)d_in[10];
    const float* gamma = (const float*)d_in[11];
    const float* beta  = (const float*)d_in[12];
    (void)n_in; (void)out_size;

    int n_nodes = in_sizes[0] / DIN;   // 10000
    int n_edges = in_sizes[2];         // 100000

    char* ws = (char*)d_ws;
    size_t off = 0;
    auto carve = [&](size_t bytes) -> void* {
        void* p = ws + off;
        off = (off + bytes + 255) & ~(size_t)255;
        return p;
    };
    unsigned short* h     = (unsigned short*)carve((size_t)n_edges * EHID * 2);  // 25.6 MB
    unsigned short* msg   = (unsigned short*)carve((size_t)n_edges * 64 * 2);    // 12.8 MB (bf16)
    float*          outb  = (float*)carve((size_t)n_nodes * HDIM * 4);
    unsigned short* outbf = (unsigned short*)carve((size_t)n_nodes * HDIM * 2);
    unsigned short* BmatT = (unsigned short*)carve((size_t)TC * 64 * 2);
    int*            offS  = (int*)carve((size_t)(n_nodes + 1) * 4);
    int*            offD  = (int*)carve((size_t)(n_nodes + 1) * 4);
    int*            curS  = (int*)carve((size_t)n_nodes * 4);
    int*            curD  = (int*)carve((size_t)n_nodes * 4);
    int*            permS = (int*)carve((size_t)n_edges * 4);
    int*            permD = (int*)carve((size_t)n_edges * 4);
    float*          stat  = (float*)carve(128 * 4 + (size_t)2 * n_nodes * 4); // stat + cntS + cntD
    int*            cntS  = (int*)(stat + 128);
    int*            cntD  = cntS + n_nodes;
    unsigned short* T     = (unsigned short*)(ws + off);
    size_t avail = ws_size > off ? ws_size - off : 0;
    long tcap = (long)(avail / ((size_t)TC * 2));   // ws-capacity bound (node rows)
    if (tcap > n_nodes) tcap = n_nodes;
    if (tcap < 64) tcap = 64;
    long tchunk = tcap;   // R7: chunking measured neutral -> single chunk, fewer launches

    hipMemsetAsync(stat, 0, 128 * 4 + (size_t)2 * n_nodes * 4, stream);

    int nbN = (n_nodes + 3) / 4;            // 2500
    int nbE = (n_edges + 63) / 64;          // 1563 (MFMA edge path: 64 edges/block)
    int nbB = (TC * 64 + 255) / 256;        // 2064
    int nbH = (n_edges + 255) / 256;        // 391
    k_pro<<<dim3(nbN + nbE + nbB + nbH), 256, 0, stream>>>(
        nf, W0, b0, outb, outbf, ef, We1, be1, h, We2, be2, BmatT,
        src, dst, cntS, cntD, n_nodes, n_edges, nbN, nbE, nbB);
    k_scan<<<dim3(2), 256, 0, stream>>>(cntS, cntD, offS, offD, curS, curD, n_nodes, n_edges);
    k_perm<<<dim3((n_edges + 255) / 256), 256, 0, stream>>>(src, dst, curS, curD, permS, permD, n_edges);

    for (int step = 0; step < STEPS; ++step) {
        for (long n0 = 0; n0 < n_nodes; n0 += tchunk) {
            long n1 = n0 + tchunk; if (n1 > n_nodes) n1 = n_nodes;
            long cnt = n1 - n0;
            k_T<<<dim3(17, (cnt + 127) / 128), 256, 0, stream>>>(
                outbf, BmatT, T, (int)n0, (int)n1);
            k_msg<<<dim3((cnt + 3) / 4), 256, 0, stream>>>(
                h, T, offS, permS, msg, (int)n0, (int)n1);
        }
        k_agg<<<dim3((n_nodes + 3) / 4), 256, 0, stream>>>(msg, offD, permD, cbias, outb, outbf, n_nodes);
    }

    k_bn_stats<<<dim3(64), 256, 0, stream>>>(outb, stat, n_nodes);
    k_bn_apply<<<dim3((n_nodes * HDIM + 255) / 256), 256, 0, stream>>>(
        outb, stat, gamma, beta, (float*)d_out, n_nodes * HDIM, n_nodes);
}

// Round 5
// 418.637 us; speedup vs baseline: 1.9120x; 1.0097x over previous
//
#include <hip/hip_runtime.h>
#include <stdint.h>

#define DIN   64
#define HDIM  64
#define EIN   16
#define EHID  128     // edge hidden width
#define HH    4096    // HDIM*HDIM
#define TC    8256    // T cols: 8192 main + 64 bias
#define STEPS 3

typedef short bf16x8 __attribute__((ext_vector_type(8)));
typedef float f32x4  __attribute__((ext_vector_type(4)));

__device__ __forceinline__ unsigned short f32_to_bf16(float f) {
    union { float f; uint32_t u; } v; v.f = f;
    uint32_t r = v.u + 0x7fffu + ((v.u >> 16) & 1u);   // RNE
    return (unsigned short)(r >> 16);
}
__device__ __forceinline__ float bfu_to_f(unsigned short u) {
    union { uint32_t u; float f; } v; v.u = (uint32_t)u << 16; return v.f;
}

// ---- merged prologue: [0,nbN) node_mlp | [nbN,+nbE) edge_mlp(MFMA) | [+nbB) bmat | rest hist ----
__global__ void k_pro(const float* __restrict__ nf, const float* __restrict__ W0,
                      const float* __restrict__ b0, float* __restrict__ outb,
                      unsigned short* __restrict__ outbf,
                      const float* __restrict__ ef, const float* __restrict__ We1,
                      const float* __restrict__ be1, unsigned short* __restrict__ h,
                      const float* __restrict__ We2, const float* __restrict__ be2,
                      unsigned short* __restrict__ BmatT,
                      const int* __restrict__ src, const int* __restrict__ dst,
                      int* __restrict__ cntS, int* __restrict__ cntD,
                      int n_nodes, int n_edges, int nbN, int nbE, int nbB) {
    __shared__ float smem[DIN * HDIM];   // 16 KB (node path only)
    int b = blockIdx.x, tid = threadIdx.x;
    if (b < nbN) {
        // node MLP: out[n,o] = relu(n_feat[n,:]@W0[:,o]+b0[o]); 4 nodes/block
        for (int i = tid; i < DIN * HDIM; i += 256) smem[i] = W0[i];
        __syncthreads();
        int node = b * 4 + (tid >> 6);
        int o = tid & 63;
        if (node >= n_nodes) return;
        float xr = nf[node * DIN + o];
        float acc = b0[o];
#pragma unroll 8
        for (int i = 0; i < DIN; ++i)
            acc += __shfl(xr, i, 64) * smem[i * HDIM + o];
        float v = fmaxf(acc, 0.f);
        outb[node * HDIM + o] = v;
        outbf[node * HDIM + o] = f32_to_bf16(v);
    } else if (b < nbN + nbE) {
        // edge MLP via MFMA: 64 edges/block (16/wave), K=16 zero-padded to 32.
        // h stored with per-64-group col perm sigma (inverse baked into BmatT k-index).
        int wave = tid >> 6, lane = tid & 63;
        int r = lane & 15, q = lane >> 4;
        int e0 = (b - nbN) * 64 + wave * 16;
        if (e0 >= n_edges) return;           // wave-uniform
        bf16x8 afr = (bf16x8){};
        bf16x8 bfr[8];
#pragma unroll
        for (int nt = 0; nt < 8; ++nt) bfr[nt] = (bf16x8){};
        if (q < 2) {
            int ea = e0 + r; if (ea >= n_edges) ea = n_edges - 1;
            const float* xa = ef + (size_t)ea * EIN + q * 8;
#pragma unroll
            for (int j = 0; j < 8; ++j) afr[j] = (short)f32_to_bf16(xa[j]);
#pragma unroll
            for (int nt = 0; nt < 8; ++nt)
#pragma unroll
                for (int j = 0; j < 8; ++j)
                    bfr[nt][j] = (short)f32_to_bf16(We1[(q * 8 + j) * EHID + nt * 16 + r]);
        }
        f32x4 acc[8];
#pragma unroll
        for (int nt = 0; nt < 8; ++nt)
            acc[nt] = __builtin_amdgcn_mfma_f32_16x16x32_bf16(afr, bfr[nt], (f32x4){}, 0, 0, 0);
        float bias[8];
#pragma unroll
        for (int nt = 0; nt < 8; ++nt) bias[nt] = be1[nt * 16 + r];
#pragma unroll
        for (int rg = 0; rg < 4; ++rg) {
            int e = e0 + q * 4 + rg;         // C/D: col=lane&15, row=quad*4+reg
            if (e >= n_edges) continue;
            ushort4 pk0, pk1;
            pk0.x = f32_to_bf16(fmaxf(acc[0][rg] + bias[0], 0.f));
            pk0.y = f32_to_bf16(fmaxf(acc[1][rg] + bias[1], 0.f));
            pk0.z = f32_to_bf16(fmaxf(acc[2][rg] + bias[2], 0.f));
            pk0.w = f32_to_bf16(fmaxf(acc[3][rg] + bias[3], 0.f));
            pk1.x = f32_to_bf16(fmaxf(acc[4][rg] + bias[4], 0.f));
            pk1.y = f32_to_bf16(fmaxf(acc[5][rg] + bias[5], 0.f));
            pk1.z = f32_to_bf16(fmaxf(acc[6][rg] + bias[6], 0.f));
            pk1.w = f32_to_bf16(fmaxf(acc[7][rg] + bias[7], 0.f));
            *(ushort4*)(h + (size_t)e * EHID + 4 * r) = pk0;
            *(ushort4*)(h + (size_t)e * EHID + 64 + 4 * r) = pk1;
        }
    } else if (b < nbN + nbE + nbB) {
        // BmatT: epilogue-pack perm (128-group main / 64-group bias) + T'' layout + h-perm sigma
        int t = (b - nbN - nbE) * 256 + tid;
        if (t >= TC * 64) return;
        int c = t >> 6, i = t & 63;
        int m;
        if (c < 8192) {
            int g = c & 127;                       // mfma col nt*16+r -> mem col 8r+nt
            m = (c & ~127) + 8 * (g & 15) + (g >> 4);
        } else {
            int g = c & 63;                        // bias block keeps 4r+nt
            m = (c & ~63) + 4 * (g & 15) + (g >> 4);
        }
        float v;
        if (m < 8192) {
            int p = ((m >> 11) << 5) | (m & 31);                     // stored h position
            int k = (p & 64) + ((p & 3) << 4) + ((p >> 2) & 15);     // true h channel
            int o = (m >> 5) & 63;
            v = We2[k * HH + i * 64 + o];
        } else {
            v = be2[i * 64 + (m - 8192)];
        }
        BmatT[t] = f32_to_bf16(v);
    } else {
        // histogram src and dst
        int e = (b - nbN - nbE - nbB) * 256 + tid;
        if (e >= n_edges) return;
        atomicAdd(&cntS[src[e]], 1);
        atomicAdd(&cntD[dst[e]], 1);
    }
}

// T[n, m] = sum_i x[n,i]*B[i,m], bf16 out.
// NEW: T stored PANEL-MAJOR: T[p][n][512] for p=0..15 (main) + bias panel [n][64]
// at offset 16*pstr. A k_T block (x=panel, y=128 nodes) now writes ONE DENSE
// 128KB region (consecutive nodes x 1KB chunks) instead of 128 chunks of 1KB
// at 16.5KB stride -> DRAM page locality ~= the fill kernel's (6.5 TB/s) vs
// the measured 4.1 TB/s of the strided layout. k_msg reads are unchanged in
// shape: fragment (s,nt) spans exactly panel s*4+nt, offset r*32+q*8 (1KB/instr).
__global__ void k_T(const unsigned short* __restrict__ outbf, const unsigned short* __restrict__ BmatT,
                    unsigned short* __restrict__ T, int n0, int n1) {
    int wave = threadIdx.x >> 6, lane = threadIdx.x & 63;
    int r = lane & 15, q = lane >> 4;
    int eb = n0 + blockIdx.y * 128;
    size_t pstr = (size_t)(n1 - n0) * 512;   // ushorts per panel
    if (blockIdx.x < 16) {
        int cb = blockIdx.x * 512 + wave * 128;          // BmatT column base (unchanged)
        unsigned short* Tp = T + (size_t)blockIdx.x * pstr;
        bf16x8 bfr[8][2];
#pragma unroll
        for (int nt = 0; nt < 8; ++nt) {
            size_t cofs = (size_t)(cb + nt * 16 + r) * 64;
            bfr[nt][0] = *(const bf16x8*)(BmatT + cofs + q * 8);
            bfr[nt][1] = *(const bf16x8*)(BmatT + cofs + 32 + q * 8);
        }
#pragma unroll
        for (int mt = 0; mt < 8; ++mt) {
            int e = eb + mt * 16 + r;
            if (e >= n1) e = n1 - 1;
            bf16x8 afr0 = *(const bf16x8*)(outbf + (size_t)e * 64 + q * 8);
            bf16x8 afr1 = *(const bf16x8*)(outbf + (size_t)e * 64 + 32 + q * 8);
            f32x4 acc[8];
#pragma unroll
            for (int nt = 0; nt < 8; ++nt) {
                acc[nt] = __builtin_amdgcn_mfma_f32_16x16x32_bf16(afr0, bfr[nt][0], (f32x4){}, 0, 0, 0);
                acc[nt] = __builtin_amdgcn_mfma_f32_16x16x32_bf16(afr1, bfr[nt][1], acc[nt], 0, 0, 0);
            }
#pragma unroll
            for (int rg = 0; rg < 4; ++rg) {
                int n = eb + mt * 16 + q * 4 + rg;   // C/D: col=lane&15, row=quad*4+reg
                if (n >= n1) continue;
                ushort4 pa, pb;
                pa.x = f32_to_bf16(acc[0][rg]); pa.y = f32_to_bf16(acc[1][rg]);
                pa.z = f32_to_bf16(acc[2][rg]); pa.w = f32_to_bf16(acc[3][rg]);
                pb.x = f32_to_bf16(acc[4][rg]); pb.y = f32_to_bf16(acc[5][rg]);
                pb.z = f32_to_bf16(acc[6][rg]); pb.w = f32_to_bf16(acc[7][rg]);
                uint4 pk = { ((uint32_t)pa.y << 16) | pa.x, ((uint32_t)pa.w << 16) | pa.z,
                             ((uint32_t)pb.y << 16) | pb.x, ((uint32_t)pb.w << 16) | pb.z };
                *(uint4*)(Tp + (size_t)(n - n0) * 512 + wave * 128 + 8 * r) = pk;
            }
        }
    } else {
        if (wave != 0) return;               // bias tail: 64 cols, bias panel
        int cb = 8192;
        unsigned short* Tp = T + 16 * pstr;
        bf16x8 bfr[4][2];
#pragma unroll
        for (int nt = 0; nt < 4; ++nt) {
            size_t cofs = (size_t)(cb + nt * 16 + r) * 64;
            bfr[nt][0] = *(const bf16x8*)(BmatT + cofs + q * 8);
            bfr[nt][1] = *(const bf16x8*)(BmatT + cofs + 32 + q * 8);
        }
#pragma unroll
        for (int mt = 0; mt < 8; ++mt) {
            int e = eb + mt * 16 + r;
            if (e >= n1) e = n1 - 1;
            bf16x8 afr0 = *(const bf16x8*)(outbf + (size_t)e * 64 + q * 8);
            bf16x8 afr1 = *(const bf16x8*)(outbf + (size_t)e * 64 + 32 + q * 8);
            f32x4 acc[4];
#pragma unroll
            for (int nt = 0; nt < 4; ++nt) {
                acc[nt] = __builtin_amdgcn_mfma_f32_16x16x32_bf16(afr0, bfr[nt][0], (f32x4){}, 0, 0, 0);
                acc[nt] = __builtin_amdgcn_mfma_f32_16x16x32_bf16(afr1, bfr[nt][1], acc[nt], 0, 0, 0);
            }
#pragma unroll
            for (int rg = 0; rg < 4; ++rg) {
                int n = eb + mt * 16 + q * 4 + rg;
                if (n >= n1) continue;
                ushort4 pk;
                pk.x = f32_to_bf16(acc[0][rg]);
                pk.y = f32_to_bf16(acc[1][rg]);
                pk.z = f32_to_bf16(acc[2][rg]);
                pk.w = f32_to_bf16(acc[3][rg]);
                *(ushort4*)(Tp + (size_t)(n - n0) * 64 + 4 * r) = pk;
            }
        }
    }
}

// per src-node wave, MFMA: msg[tile of 16 edges][64 o] = h[edges, 0:128] @ T''[n]
// T is panel-major (see k_T); fragment (s,nt) lives in panel s*4+nt at offset
// (n-n0)*512 + r*32 + q*8. msg stored col-permuted IN BF16: mem col 4r+nt holds
// mfma col nt*16+r; k_agg applies the inverse perm.
__global__ void k_msg(const unsigned short* __restrict__ h, const unsigned short* __restrict__ T,
                      const int* __restrict__ offS, const int* __restrict__ permS,
                      unsigned short* __restrict__ msg, int n0, int n1) {
    int wave = threadIdx.x >> 6, lane = threadIdx.x & 63;
    int n = n0 + blockIdx.x * 4 + wave;
    if (n >= n1) return;
    int beg = offS[n], end = offS[n + 1];
    if (beg == end) return;
    int r = lane & 15, q = lane >> 4;
    size_t pstr = (size_t)(n1 - n0) * 512;
    const unsigned short* Tb = T + (size_t)(n - n0) * 512;
    float bias[4];
#pragma unroll
    for (int nt = 0; nt < 4; ++nt)
        bias[nt] = bfu_to_f(T[16 * pstr + (size_t)(n - n0) * 64 + nt * 16 + r]);
    for (int j0 = beg; j0 < end; j0 += 16) {
        int jc = j0 + r; if (jc >= end) jc = end - 1;
        int e = permS[jc];
        const unsigned short* he = h + (size_t)e * EHID;
        f32x4 acc[4] = {};
#pragma unroll
        for (int s = 0; s < 4; ++s) {        // K = 128 = 4*32
            bf16x8 afr = *(const bf16x8*)(he + s * 32 + q * 8);
#pragma unroll
            for (int nt = 0; nt < 4; ++nt) {
                bf16x8 bfr = *(const bf16x8*)(Tb + (size_t)(s * 4 + nt) * pstr + r * 32 + q * 8);
                acc[nt] = __builtin_amdgcn_mfma_f32_16x16x32_bf16(afr, bfr, acc[nt], 0, 0, 0);
            }
        }
#pragma unroll
        for (int rg = 0; rg < 4; ++rg) {
            int jr = j0 + q * 4 + rg;
            if (jr >= end) continue;
            int er = permS[jr];
            ushort4 pk;
            pk.x = f32_to_bf16(acc[0][rg] + bias[0]);
            pk.y = f32_to_bf16(acc[1][rg] + bias[1]);
            pk.z = f32_to_bf16(acc[2][rg] + bias[2]);
            pk.w = f32_to_bf16(acc[3][rg] + bias[3]);
            *(ushort4*)(msg + (size_t)er * 64 + 4 * r) = pk;
        }
    }
}

// exclusive prefix sum (one block per array; blockIdx.x: 0=S, 1=D)
__global__ void k_scan(const int* __restrict__ cntS, const int* __restrict__ cntD,
                       int* __restrict__ offS, int* __restrict__ offD,
                       int* __restrict__ curS, int* __restrict__ curD, int n, int total) {
    const int* cnt = blockIdx.x ? cntD : cntS;
    int* off = blockIdx.x ? offD : offS;
    int* cur = blockIdx.x ? curD : curS;
    __shared__ int part[256];
    int tid = threadIdx.x;
    int chunk = (n + 255) / 256;
    int c0 = tid * chunk, c1 = c0 + chunk; if (c1 > n) c1 = n; if (c0 > n) c0 = n;
    int s = 0;
    for (int i = c0; i < c1; ++i) s += cnt[i];
    part[tid] = s;
    __syncthreads();
    for (int st = 1; st < 256; st <<= 1) {
        int v = (tid >= st) ? part[tid - st] : 0;
        __syncthreads();
        part[tid] += v;
        __syncthreads();
    }
    int run = tid ? part[tid - 1] : 0;
    for (int i = c0; i < c1; ++i) { off[i] = run; cur[i] = run; run += cnt[i]; }
    if (tid == 0) off[n] = total;
}

__global__ void k_perm(const int* __restrict__ src, const int* __restrict__ dst,
                       int* __restrict__ curS, int* __restrict__ curD,
                       int* __restrict__ permS, int* __restrict__ permD, int n_edges) {
    int e = blockIdx.x * 256 + threadIdx.x;
    if (e >= n_edges) return;
    permS[atomicAdd(&curS[src[e]], 1)] = e;
    permD[atomicAdd(&curD[dst[e]], 1)] = e;
}

// per dst-node wave: out[d] = relu(sum msg + cbias); atomic-free.
// msg cols are stored permuted bf16: lane's stored col l is semantic o=(l&3)*16+(l>>2).
__global__ void k_agg(const unsigned short* __restrict__ msg, const int* __restrict__ offD,
                      const int* __restrict__ permD, const float* __restrict__ cbias,
                      float* __restrict__ outb, unsigned short* __restrict__ outbf, int n_nodes) {
    int wave = threadIdx.x >> 6, lane = threadIdx.x & 63;
    int d = blockIdx.x * 4 + wave;
    if (d >= n_nodes) return;
    int o = (lane & 3) * 16 + (lane >> 2);
    float acc = 0.f;
    int end = offD[d + 1];
    for (int j = offD[d]; j < end; ++j)
        acc += bfu_to_f(msg[(size_t)permD[j] * 64 + lane]);
    float v = fmaxf(acc + cbias[o], 0.f);
    outb[(size_t)d * 64 + o] = v;
    outbf[(size_t)d * 64 + o] = f32_to_bf16(v);
}

// grid MUST be 64 blocks (row stride 256 hardcoded)
__global__ void k_bn_stats(const float* __restrict__ out, float* __restrict__ stat, int n_nodes) {
    __shared__ float s1[256], s2[256];
    int tid = threadIdx.x;
    int f = tid & 63, g = tid >> 6;
    float sum = 0.f, ss = 0.f;
    for (int r = blockIdx.x * 4 + g; r < n_nodes; r += 256) {
        float v = out[r * HDIM + f];
        sum += v; ss += v * v;
    }
    s1[tid] = sum; s2[tid] = ss;
    __syncthreads();
    if (tid < 64) {
        float A = s1[tid] + s1[64 + tid] + s1[128 + tid] + s1[192 + tid];
        float B = s2[tid] + s2[64 + tid] + s2[128 + tid] + s2[192 + tid];
        atomicAdd(&stat[tid], A);
        atomicAdd(&stat[64 + tid], B);
    }
}

// bn_final fused in: every thread derives scale/shift from stat (identical arith)
__global__ void k_bn_apply(const float* __restrict__ out, const float* __restrict__ stat,
                           const float* __restrict__ gamma, const float* __restrict__ beta,
                           float* __restrict__ y, int n, int n_nodes) {
    int t = blockIdx.x * 256 + threadIdx.x;
    if (t >= n) return;
    int f = t & 63;
    float mean = stat[f] / n_nodes;
    float var  = stat[64 + f] / n_nodes - mean * mean;   // population var
    float inv  = rsqrtf(var + 1e-5f);
    float scale = gamma[f] * inv;
    float shift = beta[f] - mean * scale;
    y[t] = out[t] * scale + shift;
}

extern "C" void kernel_launch(void* const* d_in, const int* in_sizes, int n_in,
                              void* d_out, int out_size, void* d_ws, size_t ws_size,
                              hipStream_t stream) {
    const float* nf    = (const float*)d_in[0];
    const float* ef    = (const float*)d_in[1];
    const int*   src   = (const int*)d_in[2];
    const int*   dst   = (const int*)d_in[3];
    const float* W0    = (const float*)d_in[4];
    const float* b0    = (const float*)d_in[5];
    const float* We1   = (const float*)d_in[6];
    const float* be1   = (const float*)d_in[7];
    const float* We2   = (const float*)d_in[8];
    const float* be2   = (const float*)d_in[9];
    const float* cbias = (const float*)d_in[10];
    const float* gamma = (const float*)d_in[11];
    const float* beta  = (const float*)d_in[12];
    (void)n_in; (void)out_size;

    int n_nodes = in_sizes[0] / DIN;   // 10000
    int n_edges = in_sizes[2];         // 100000

    char* ws = (char*)d_ws;
    size_t off = 0;
    auto carve = [&](size_t bytes) -> void* {
        void* p = ws + off;
        off = (off + bytes + 255) & ~(size_t)255;
        return p;
    };
    unsigned short* h     = (unsigned short*)carve((size_t)n_edges * EHID * 2);  // 25.6 MB
    unsigned short* msg   = (unsigned short*)carve((size_t)n_edges * 64 * 2);    // 12.8 MB (bf16)
    float*          outb  = (float*)carve((size_t)n_nodes * HDIM * 4);
    unsigned short* outbf = (unsigned short*)carve((size_t)n_nodes * HDIM * 2);
    unsigned short* BmatT = (unsigned short*)carve((size_t)TC * 64 * 2);
    int*            offS  = (int*)carve((size_t)(n_nodes + 1) * 4);
    int*            offD  = (int*)carve((size_t)(n_nodes + 1) * 4);
    int*            curS  = (int*)carve((size_t)n_nodes * 4);
    int*            curD  = (int*)carve((size_t)n_nodes * 4);
    int*            permS = (int*)carve((size_t)n_edges * 4);
    int*            permD = (int*)carve((size_t)n_edges * 4);
    float*          stat  = (float*)carve(128 * 4 + (size_t)2 * n_nodes * 4); // stat + cntS + cntD
    int*            cntS  = (int*)(stat + 128);
    int*            cntD  = cntS + n_nodes;
    unsigned short* T     = (unsigned short*)(ws + off);
    size_t avail = ws_size > off ? ws_size - off : 0;
    long tcap = (long)(avail / ((size_t)TC * 2));   // ws-capacity bound (node rows)
    if (tcap > n_nodes) tcap = n_nodes;
    if (tcap < 64) tcap = 64;
    long tchunk = tcap;   // R7: chunking measured neutral -> single chunk, fewer launches

    hipMemsetAsync(stat, 0, 128 * 4 + (size_t)2 * n_nodes * 4, stream);

    int nbN = (n_nodes + 3) / 4;            // 2500
    int nbE = (n_edges + 63) / 64;          // 1563 (MFMA edge path: 64 edges/block)
    int nbB = (TC * 64 + 255) / 256;        // 2064
    int nbH = (n_edges + 255) / 256;        // 391
    k_pro<<<dim3(nbN + nbE + nbB + nbH), 256, 0, stream>>>(
        nf, W0, b0, outb, outbf, ef, We1, be1, h, We2, be2, BmatT,
        src, dst, cntS, cntD, n_nodes, n_edges, nbN, nbE, nbB);
    k_scan<<<dim3(2), 256, 0, stream>>>(cntS, cntD, offS, offD, curS, curD, n_nodes, n_edges);
    k_perm<<<dim3((n_edges + 255) / 256), 256, 0, stream>>>(src, dst, curS, curD, permS, permD, n_edges);

    for (int step = 0; step < STEPS; ++step) {
        for (long n0 = 0; n0 < n_nodes; n0 += tchunk) {
            long n1 = n0 + tchunk; if (n1 > n_nodes) n1 = n_nodes;
            long cnt = n1 - n0;
            k_T<<<dim3(17, (cnt + 127) / 128), 256, 0, stream>>>(
                outbf, BmatT, T, (int)n0, (int)n1);
            k_msg<<<dim3((cnt + 3) / 4), 256, 0, stream>>>(
                h, T, offS, permS, msg, (int)n0, (int)n1);
        }
        k_agg<<<dim3((n_nodes + 3) / 4), 256, 0, stream>>>(msg, offD, permD, cbias, outb, outbf, n_nodes);
    }

    k_bn_stats<<<dim3(64), 256, 0, stream>>>(outb, stat, n_nodes);
    k_bn_apply<<<dim3((n_nodes * HDIM + 255) / 256), 256, 0, stream>>>(
        outb, stat, gamma, beta, (float*)d_out, n_nodes * HDIM, n_nodes);
}